// Round 5
// baseline (322.234 us; speedup 1.0000x reference)
//
#include <hip/hip_runtime.h>
#include <hip/hip_cooperative_groups.h>
#include <math.h>

namespace cg = cooperative_groups;

// Problem constants (fixed by setup_inputs): gts/preds [4, 8192, 3] fp32.
#define BB 4
#define NPTS 8192
#define THREADS 256
#define QPT 4                           // queries per thread in min phase
#define QPB (THREADS * QPT)             // 1024 queries per block
#define CHUNKSQ (NPTS / QPB)            // 8 query chunks per (dir, b)
#define SLICES 16                       // ref-dimension split
#define RPS (NPTS / SLICES)             // 512 refs per slice
#define NQ_TOTAL (2 * BB * NPTS)        // 65536 (dir, b, q) query points
#define NBLOCKS (SLICES * 2 * BB * CHUNKSQ)   // 1024 blocks = 4/CU (coop-safe)
#define MQPB (NQ_TOTAL / NBLOCKS)       // 64 merge queries per block

// ws layout:
//   [0, 1 MiB)      packed: NQ_TOTAL float4 [x,y,z,|p|^2], set0=gts set1=preds
//   [1 MiB, 5 MiB)  minpart: SLICES * NQ_TOTAL floats (partial min of rr-2*q.r)

// ---------------------------------------------------------------------------
// Shared phase bodies (used by both the fused coop kernel and the fallback).
// ---------------------------------------------------------------------------
__device__ __forceinline__ void pack_body(int gidx,
                                          const float* __restrict__ gts,
                                          const float* __restrict__ preds,
                                          float4* __restrict__ packed,
                                          float* __restrict__ out) {
    if (gidx < NQ_TOTAL) {
        int set  = gidx / (BB * NPTS);
        int pidx = gidx - set * (BB * NPTS);
        const float* src = set ? preds : gts;
        float x = src[pidx * 3 + 0];
        float y = src[pidx * 3 + 1];
        float z = src[pidx * 3 + 2];
        packed[gidx] = make_float4(x, y, z, fmaf(x, x, fmaf(y, y, z * z)));
    }
    if (gidx < BB) out[gidx] = 0.0f;
}

// Partial min over one ref slice; 4 queries/thread, wave-uniform ref loads,
// 3 fma + 1 min per pair (-2 folded into query registers).
__device__ __forceinline__ void min_body(int blk, int tid,
                                         const float4* __restrict__ packed,
                                         float* __restrict__ minpart) {
    int slice = blk / (2 * BB * CHUNKSQ);
    int rem   = blk - slice * (2 * BB * CHUNKSQ);
    int dir   = rem / (BB * CHUNKSQ);
    rem       = rem - dir * (BB * CHUNKSQ);
    int b     = rem / CHUNKSQ;
    int chunk = rem - b * CHUNKSQ;

    const float4* qbase = packed + (dir == 0 ? 1 : 0) * (BB * NPTS) + b * NPTS;
    const float4* rbase = packed + (dir == 0 ? 0 : 1) * (BB * NPTS) + b * NPTS
                        + slice * RPS;

    int qi = chunk * QPB + tid;
    float4 q0 = qbase[qi + 0 * THREADS];
    float4 q1 = qbase[qi + 1 * THREADS];
    float4 q2 = qbase[qi + 2 * THREADS];
    float4 q3 = qbase[qi + 3 * THREADS];
    float c0x = -2.0f * q0.x, c0y = -2.0f * q0.y, c0z = -2.0f * q0.z;
    float c1x = -2.0f * q1.x, c1y = -2.0f * q1.y, c1z = -2.0f * q1.z;
    float c2x = -2.0f * q2.x, c2y = -2.0f * q2.y, c2z = -2.0f * q2.z;
    float c3x = -2.0f * q3.x, c3y = -2.0f * q3.y, c3z = -2.0f * q3.z;

    const float INF = 3.0e38f;
    float m00 = INF, m01 = INF, m02 = INF, m03 = INF;
    float m10 = INF, m11 = INF, m12 = INF, m13 = INF;
    float m20 = INF, m21 = INF, m22 = INF, m23 = INF;
    float m30 = INF, m31 = INF, m32 = INF, m33 = INF;

    #pragma unroll 2
    for (int j = 0; j < RPS; j += 4) {
        float4 r0 = rbase[j + 0];
        float4 r1 = rbase[j + 1];
        float4 r2 = rbase[j + 2];
        float4 r3 = rbase[j + 3];
        m00 = fminf(m00, fmaf(c0x, r0.x, fmaf(c0y, r0.y, fmaf(c0z, r0.z, r0.w))));
        m01 = fminf(m01, fmaf(c0x, r1.x, fmaf(c0y, r1.y, fmaf(c0z, r1.z, r1.w))));
        m02 = fminf(m02, fmaf(c0x, r2.x, fmaf(c0y, r2.y, fmaf(c0z, r2.z, r2.w))));
        m03 = fminf(m03, fmaf(c0x, r3.x, fmaf(c0y, r3.y, fmaf(c0z, r3.z, r3.w))));
        m10 = fminf(m10, fmaf(c1x, r0.x, fmaf(c1y, r0.y, fmaf(c1z, r0.z, r0.w))));
        m11 = fminf(m11, fmaf(c1x, r1.x, fmaf(c1y, r1.y, fmaf(c1z, r1.z, r1.w))));
        m12 = fminf(m12, fmaf(c1x, r2.x, fmaf(c1y, r2.y, fmaf(c1z, r2.z, r2.w))));
        m13 = fminf(m13, fmaf(c1x, r3.x, fmaf(c1y, r3.y, fmaf(c1z, r3.z, r3.w))));
        m20 = fminf(m20, fmaf(c2x, r0.x, fmaf(c2y, r0.y, fmaf(c2z, r0.z, r0.w))));
        m21 = fminf(m21, fmaf(c2x, r1.x, fmaf(c2y, r1.y, fmaf(c2z, r1.z, r1.w))));
        m22 = fminf(m22, fmaf(c2x, r2.x, fmaf(c2y, r2.y, fmaf(c2z, r2.z, r2.w))));
        m23 = fminf(m23, fmaf(c2x, r3.x, fmaf(c2y, r3.y, fmaf(c2z, r3.z, r3.w))));
        m30 = fminf(m30, fmaf(c3x, r0.x, fmaf(c3y, r0.y, fmaf(c3z, r0.z, r0.w))));
        m31 = fminf(m31, fmaf(c3x, r1.x, fmaf(c3y, r1.y, fmaf(c3z, r1.z, r1.w))));
        m32 = fminf(m32, fmaf(c3x, r2.x, fmaf(c3y, r2.y, fmaf(c3z, r2.z, r2.w))));
        m33 = fminf(m33, fmaf(c3x, r3.x, fmaf(c3y, r3.y, fmaf(c3z, r3.z, r3.w))));
    }

    int dirb = dir * BB + b;
    float* dst = minpart + slice * NQ_TOTAL + dirb * NPTS;
    dst[qi + 0 * THREADS] = fminf(fminf(m00, m01), fminf(m02, m03));
    dst[qi + 1 * THREADS] = fminf(fminf(m10, m11), fminf(m12, m13));
    dst[qi + 2 * THREADS] = fminf(fminf(m20, m21), fminf(m22, m23));
    dst[qi + 3 * THREADS] = fminf(fminf(m30, m31), fminf(m32, m33));
}

// Merge slices, add |q|^2, sqrt, wave-reduce, atomicAdd. One wave of 64 q.
__device__ __forceinline__ void merge_body(int q, int lane,
                                           const float4* __restrict__ packed,
                                           const float* __restrict__ minpart,
                                           float* __restrict__ out) {
    int dirb   = q >> 13;            // q / NPTS
    int qlocal = q & (NPTS - 1);
    int dir    = dirb >> 2;          // dirb / BB
    int b      = dirb & (BB - 1);

    float m = 3.0e38f;
    #pragma unroll
    for (int s = 0; s < SLICES; ++s)
        m = fminf(m, minpart[s * NQ_TOTAL + q]);

    float qq = packed[(dir == 0 ? 1 : 0) * (BB * NPTS) + b * NPTS + qlocal].w;
    float d = sqrtf(fmaxf(qq + m, 0.0f));

    float sum = d;
    #pragma unroll
    for (int off = 32; off > 0; off >>= 1)
        sum += __shfl_down(sum, off, 64);

    if (lane == 0)
        atomicAdd(out + b, sum);
}

// ---------------------------------------------------------------------------
// Fused cooperative kernel: pack -> grid.sync -> slice-min -> grid.sync -> merge
// 1024 blocks x 256 threads (4 blocks/CU).
// ---------------------------------------------------------------------------
__global__ __launch_bounds__(THREADS, 4) void chamfer_fused(
    const float* __restrict__ gts, const float* __restrict__ preds,
    float4* __restrict__ packed, float* __restrict__ minpart,
    float* __restrict__ out)
{
    cg::grid_group grid = cg::this_grid();

    pack_body(blockIdx.x * THREADS + threadIdx.x, gts, preds, packed, out);
    grid.sync();
    min_body(blockIdx.x, threadIdx.x, packed, minpart);
    grid.sync();
    if (threadIdx.x < 64)
        merge_body(blockIdx.x * MQPB + threadIdx.x, threadIdx.x,
                   packed, minpart, out);
}

// ---------------------------------------------------------------------------
// Fallback path: same phases as separate kernels.
// ---------------------------------------------------------------------------
__global__ __launch_bounds__(THREADS) void pack_kernel(
    const float* __restrict__ gts, const float* __restrict__ preds,
    float4* __restrict__ packed, float* __restrict__ out) {
    pack_body(blockIdx.x * THREADS + threadIdx.x, gts, preds, packed, out);
}

__global__ __launch_bounds__(THREADS) void min_kernel(
    const float4* __restrict__ packed, float* __restrict__ minpart) {
    min_body(blockIdx.x, threadIdx.x, packed, minpart);
}

__global__ __launch_bounds__(64) void merge_kernel(
    const float4* __restrict__ packed, const float* __restrict__ minpart,
    float* __restrict__ out) {
    merge_body(blockIdx.x * 64 + threadIdx.x, threadIdx.x, packed, minpart, out);
}

extern "C" void kernel_launch(void* const* d_in, const int* in_sizes, int n_in,
                              void* d_out, int out_size, void* d_ws, size_t ws_size,
                              hipStream_t stream) {
    const float* gts   = (const float*)d_in[0];
    const float* preds = (const float*)d_in[1];
    float* out = (float*)d_out;

    float4* packed  = (float4*)d_ws;
    float*  minpart = (float*)((char*)d_ws + (size_t)NQ_TOTAL * sizeof(float4));

    void* args[] = {(void*)&gts, (void*)&preds, (void*)&packed,
                    (void*)&minpart, (void*)&out};
    hipError_t st = hipLaunchCooperativeKernel((const void*)chamfer_fused,
                                               dim3(NBLOCKS), dim3(THREADS),
                                               args, 0, stream);
    if (st != hipSuccess) {
        (void)hipGetLastError();   // clear the error state, take fallback path
        pack_kernel<<<NQ_TOTAL / THREADS, THREADS, 0, stream>>>(gts, preds,
                                                                packed, out);
        min_kernel<<<NBLOCKS, THREADS, 0, stream>>>(packed, minpart);
        merge_kernel<<<NQ_TOTAL / 64, 64, 0, stream>>>(packed, minpart, out);
    }
}

// Round 6
// 107.142 us; speedup vs baseline: 3.0075x; 3.0075x over previous
//
#include <hip/hip_runtime.h>
#include <math.h>

// Problem constants: gts/preds [4, 8192, 3] fp32; out [4] fp32.
#define BB 4
#define NPTS 8192
#define THREADS 256
#define NQ_TOTAL (2 * BB * NPTS)       // 65536 points (each set packed once)
#define SLICES 2                       // ref-dim split for occupancy
#define RPS (NPTS / SLICES)            // 4096 refs per slice
#define TILES (NPTS / 32)              // 256 query tiles per (dir,b)
#define NWAVES (SLICES * 2 * BB * TILES)   // 4096 waves
#define NBLK_MIN (NWAVES / 4)          // 1024 blocks (4 waves each)

typedef __attribute__((ext_vector_type(8)))  short bf16x8;   // MFMA A/B frag
typedef __attribute__((ext_vector_type(16))) float f32x16;   // MFMA C/D frag

// ws layout:
//   refpack: NQ_TOTAL uint4 (16B/pt: bf16 [x,y,z,rr_hi,rr_lo,0,0,0])   1 MiB
//   qpack:   NQ_TOTAL uint4 (16B/pt: bf16 [-2x,-2y,-2z,1,1,0,0,0])     1 MiB
//   qq:      NQ_TOTAL float (fp32 |p|^2 of the bf16-rounded point)   256 KiB
//   minpart: SLICES * NQ_TOTAL float                                 512 KiB

__device__ __forceinline__ unsigned short f2bf(float f) {   // RNE f32->bf16
    unsigned u = __float_as_uint(f);
    u += 0x7FFF + ((u >> 16) & 1);
    return (unsigned short)(u >> 16);
}
__device__ __forceinline__ float bf2f(unsigned short h) {
    return __uint_as_float(((unsigned)h) << 16);
}

// ---------------------------------------------------------------------------
// Kernel 1: round to bf16, build MFMA-ready fragments + fp32 qq; zero out[].
// Key numerics: rr/qq computed in fp32 FROM THE ROUNDED coords, and rr fed to
// the MFMA as a 2-term bf16 split (rr_hi + rr_lo) -> d^2 = |q~-r~|^2 exactly.
// ---------------------------------------------------------------------------
__global__ __launch_bounds__(THREADS) void pack_kernel(
    const float* __restrict__ gts, const float* __restrict__ preds,
    uint4* __restrict__ refpack, uint4* __restrict__ qpack,
    float* __restrict__ qq, float* __restrict__ out) {
    int idx = blockIdx.x * THREADS + threadIdx.x;
    if (idx < BB) out[idx] = 0.0f;
    if (idx >= NQ_TOTAL) return;
    int set  = idx / (BB * NPTS);          // 0 = gts, 1 = preds
    int pidx = idx - set * (BB * NPTS);
    const float* src = set ? preds : gts;
    unsigned short hx = f2bf(src[pidx * 3 + 0]);
    unsigned short hy = f2bf(src[pidx * 3 + 1]);
    unsigned short hz = f2bf(src[pidx * 3 + 2]);
    float fx = bf2f(hx), fy = bf2f(hy), fz = bf2f(hz);
    float rr = fmaf(fx, fx, fmaf(fy, fy, fz * fz));
    unsigned short hrr = f2bf(rr);
    unsigned short hlo = f2bf(rr - bf2f(hrr));

    uint4 rv;                               // ref slots k=0..7
    rv.x = (unsigned)hx | ((unsigned)hy << 16);
    rv.y = (unsigned)hz | ((unsigned)hrr << 16);
    rv.z = (unsigned)hlo;                   // rr_lo in slot 4, slot 5 = 0
    rv.w = 0;
    refpack[idx] = rv;

    const unsigned short ONE = 0x3F80;      // 1.0 in bf16
    unsigned short nx = f2bf(-2.0f * fx);   // exact (x already bf16)
    unsigned short ny = f2bf(-2.0f * fy);
    unsigned short nz = f2bf(-2.0f * fz);
    uint4 qv;                               // query slots: [-2x,-2y,-2z,1,1,0,0,0]
    qv.x = (unsigned)nx | ((unsigned)ny << 16);
    qv.y = (unsigned)nz | ((unsigned)ONE << 16);
    qv.z = (unsigned)ONE;
    qv.w = 0;
    qpack[idx] = qv;

    qq[idx] = rr;
}

// ---------------------------------------------------------------------------
// Kernel 2: MFMA min kernel. One wave owns 32 queries (A operand, persistent)
// and scans RPS refs (B operand, 32/tile). C preloaded with qq[row] so each
// MFMA emits full d^2 = qq - 2 q.r + rr; VALU cost = 1 v_min per pair.
// D layout (m74/m101): col = lane&31 = ref n, row = (r&3)+8*(r>>2)+4*(lane>>5).
// ---------------------------------------------------------------------------
__global__ __launch_bounds__(THREADS) void min_kernel(
    const uint4* __restrict__ refpack, const uint4* __restrict__ qpack,
    const float* __restrict__ qq, float* __restrict__ minpart) {
    int wid  = threadIdx.x >> 6;
    int lane = threadIdx.x & 63;
    int gw   = blockIdx.x * 4 + wid;       // 0 .. NWAVES-1
    int slice = gw >> 11;                  // / (2*BB*TILES) = /2048
    int rem   = gw & 2047;
    int dir   = rem >> 10;                 // / (BB*TILES)
    int b     = (rem >> 8) & 3;
    int tile  = rem & 255;
    int qset  = dir ^ 1;                   // dir0: queries=preds(set1)
    int rset  = dir;                       // dir0: refs=gts(set0)

    size_t qoff = (size_t)(qset * BB + b) * NPTS + (size_t)tile * 32;
    size_t roff = (size_t)(rset * BB + b) * NPTS + (size_t)slice * RPS;
    int l31  = lane & 31;
    int half = lane >> 5;

    // A fragment: lanes 0-31 hold query l31's 8 bf16 (K slots 0-7);
    // lanes 32-63 (K slots 8-15) are zero.
    bf16x8 a = {0, 0, 0, 0, 0, 0, 0, 0};
    if (lane < 32) a = ((const bf16x8*)qpack)[qoff + l31];

    // C fragment: qq of this lane's 16 query rows (constant over the loop).
    f32x16 cq;
    #pragma unroll
    for (int r = 0; r < 16; ++r)
        cq[r] = qq[qoff + ((r & 3) + 8 * (r >> 2) + 4 * half)];

    float macc[16];
    #pragma unroll
    for (int r = 0; r < 16; ++r) macc[r] = 3.0e38f;

    const bf16x8* rp = (const bf16x8*)refpack + roff;
    #pragma unroll 2
    for (int t = 0; t < RPS / 32; ++t) {   // 128 ref tiles
        bf16x8 bfrag = {0, 0, 0, 0, 0, 0, 0, 0};
        if (lane < 32) bfrag = rp[l31];
        rp += 32;
        f32x16 d = __builtin_amdgcn_mfma_f32_32x32x16_bf16(a, bfrag, cq, 0, 0, 0);
        #pragma unroll
        for (int r = 0; r < 16; ++r)
            macc[r] = fminf(macc[r], d[r]);
    }

    // Min across the 32 lanes of each half (cols = refs), per row register.
    #pragma unroll
    for (int s = 1; s <= 16; s <<= 1) {
        #pragma unroll
        for (int r = 0; r < 16; ++r)
            macc[r] = fminf(macc[r], __shfl_xor(macc[r], s, 64));
    }

    // Lane r of each half writes row(r, half). 2 active lanes per store.
    float* mp = minpart + (size_t)slice * NQ_TOTAL
              + (size_t)(dir * BB + b) * NPTS + (size_t)tile * 32;
    #pragma unroll
    for (int r = 0; r < 16; ++r) {
        int row = (r & 3) + 8 * (r >> 2) + 4 * half;
        if (l31 == r) mp[row] = macc[r];
    }
}

// ---------------------------------------------------------------------------
// Kernel 3: merge slices, sqrt, block-reduce, atomicAdd into out[b].
// ---------------------------------------------------------------------------
__global__ __launch_bounds__(THREADS) void merge_kernel(
    const float* __restrict__ minpart, float* __restrict__ out) {
    int q = blockIdx.x * THREADS + threadIdx.x;    // 0 .. NQ_TOTAL-1
    float m = minpart[q];
    #pragma unroll
    for (int s = 1; s < SLICES; ++s)
        m = fminf(m, minpart[(size_t)s * NQ_TOTAL + q]);
    float d = sqrtf(fmaxf(m, 0.0f));
    int b = (q >> 13) & 3;                         // uniform within a block

    float sum = d;
    #pragma unroll
    for (int off = 32; off > 0; off >>= 1)
        sum += __shfl_down(sum, off, 64);

    __shared__ float wsum[THREADS / 64];
    int lane = threadIdx.x & 63;
    int wid  = threadIdx.x >> 6;
    if (lane == 0) wsum[wid] = sum;
    __syncthreads();
    if (threadIdx.x == 0)
        atomicAdd(out + b, wsum[0] + wsum[1] + wsum[2] + wsum[3]);
}

extern "C" void kernel_launch(void* const* d_in, const int* in_sizes, int n_in,
                              void* d_out, int out_size, void* d_ws, size_t ws_size,
                              hipStream_t stream) {
    const float* gts   = (const float*)d_in[0];
    const float* preds = (const float*)d_in[1];
    float* out = (float*)d_out;

    char* ws = (char*)d_ws;
    uint4* refpack = (uint4*)ws;                                   // 1 MiB
    uint4* qpack   = (uint4*)(ws + (size_t)NQ_TOTAL * 16);         // 1 MiB
    float* qq      = (float*)(ws + (size_t)NQ_TOTAL * 32);         // 256 KiB
    float* minpart = (float*)(ws + (size_t)NQ_TOTAL * 36);         // 512 KiB

    pack_kernel<<<NQ_TOTAL / THREADS, THREADS, 0, stream>>>(
        gts, preds, refpack, qpack, qq, out);

    min_kernel<<<NBLK_MIN, THREADS, 0, stream>>>(refpack, qpack, qq, minpart);

    merge_kernel<<<NQ_TOTAL / THREADS, THREADS, 0, stream>>>(minpart, out);
}

// Round 7
// 90.342 us; speedup vs baseline: 3.5668x; 1.1860x over previous
//
#include <hip/hip_runtime.h>
#include <math.h>

// Problem constants: gts/preds [4, 8192, 3] fp32; out [4] fp32.
#define BB 4
#define NPTS 8192
#define THREADS 256
#define NQ_TOTAL (2 * BB * NPTS)       // 65536 points (each set packed once)
#define SLICES 2                       // ref-dim split
#define RPS (NPTS / SLICES)            // 4096 refs per slice
#define TILES (NPTS / 32)              // 256 query tiles per (dir,b)
#define NWAVES (SLICES * 2 * BB * TILES)   // 4096 waves
#define NBLK_MIN (NWAVES / 4)          // 1024 blocks (4 waves each)

typedef __attribute__((ext_vector_type(8)))  short bf16x8;   // MFMA A/B frag
typedef __attribute__((ext_vector_type(16))) float f32x16;   // MFMA C/D frag

// ws layout:
//   refpack: NQ_TOTAL uint4  bf16 [x,y,z,rr_hi,rr_lo,1,1,0]      1 MiB
//   qpack:   NQ_TOTAL uint4  bf16 [-2x,-2y,-2z,1,1,qq_hi,qq_lo,0] 1 MiB
//   minpart: SLICES * NQ_TOTAL float                             512 KiB
// MFMA dot(A_row, B_col) = -2 q.r + rr + qq = |q-r|^2 (on bf16-rounded pts).

__device__ __forceinline__ unsigned short f2bf(float f) {   // RNE f32->bf16
    unsigned u = __float_as_uint(f);
    u += 0x7FFF + ((u >> 16) & 1);
    return (unsigned short)(u >> 16);
}
__device__ __forceinline__ float bf2f(unsigned short h) {
    return __uint_as_float(((unsigned)h) << 16);
}

// ---------------------------------------------------------------------------
// Kernel 1: round coords to bf16, build A- and B-side fragments; zero out[].
// rr/qq computed in fp32 FROM THE ROUNDED coords and fed as 2-term bf16
// splits, so d^2 = |q~-r~|^2 up to ~2^-17 relative error.
// ---------------------------------------------------------------------------
__global__ __launch_bounds__(THREADS) void pack_kernel(
    const float* __restrict__ gts, const float* __restrict__ preds,
    uint4* __restrict__ refpack, uint4* __restrict__ qpack,
    float* __restrict__ out) {
    int idx = blockIdx.x * THREADS + threadIdx.x;
    if (idx < BB) out[idx] = 0.0f;
    if (idx >= NQ_TOTAL) return;
    int set  = idx / (BB * NPTS);          // 0 = gts, 1 = preds
    int pidx = idx - set * (BB * NPTS);
    const float* src = set ? preds : gts;
    unsigned short hx = f2bf(src[pidx * 3 + 0]);
    unsigned short hy = f2bf(src[pidx * 3 + 1]);
    unsigned short hz = f2bf(src[pidx * 3 + 2]);
    float fx = bf2f(hx), fy = bf2f(hy), fz = bf2f(hz);
    float rr = fmaf(fx, fx, fmaf(fy, fy, fz * fz));
    unsigned short hrr = f2bf(rr);
    unsigned short hlo = f2bf(rr - bf2f(hrr));
    const unsigned short ONE = 0x3F80;      // 1.0 bf16

    uint4 rv;                               // B slots: [x,y,z,rrhi,rrlo,1,1,0]
    rv.x = (unsigned)hx  | ((unsigned)hy  << 16);
    rv.y = (unsigned)hz  | ((unsigned)hrr << 16);
    rv.z = (unsigned)hlo | ((unsigned)ONE << 16);
    rv.w = (unsigned)ONE;
    refpack[idx] = rv;

    unsigned short nx = f2bf(-2.0f * fx);   // exact (coords already bf16)
    unsigned short ny = f2bf(-2.0f * fy);
    unsigned short nz = f2bf(-2.0f * fz);
    uint4 qv;                               // A slots: [-2x,-2y,-2z,1,1,qqhi,qqlo,0]
    qv.x = (unsigned)nx  | ((unsigned)ny  << 16);
    qv.y = (unsigned)nz  | ((unsigned)ONE << 16);
    qv.z = (unsigned)ONE | ((unsigned)hrr << 16);
    qv.w = (unsigned)hlo;
    qpack[idx] = qv;
}

// ---------------------------------------------------------------------------
// Kernel 2: MFMA min kernel. One wave owns 32 queries (A, persistent, K slots
// 8-15 zero) and scans RPS refs, 64/iter (two B tiles vs the same A). Because
// A's upper K slots are zero, B's lanes 32-63 are don't-care -> unconditional
// full-wave loads (rp[lane&31]), no exec mask, no re-zeroing. Two MFMA
// results merge via min3 -> 0.5 VALU ops per pair.
// D layout (m74/m101): col = lane&31, row = (r&3)+8*(r>>2)+4*(lane>>5).
// ---------------------------------------------------------------------------
__global__ __launch_bounds__(THREADS) void min_kernel(
    const uint4* __restrict__ refpack, const uint4* __restrict__ qpack,
    float* __restrict__ minpart) {
    int wid  = threadIdx.x >> 6;
    int lane = threadIdx.x & 63;
    int gw   = blockIdx.x * 4 + wid;       // 0 .. NWAVES-1
    int slice = gw >> 11;                  // / (2*BB*TILES)
    int rem   = gw & 2047;
    int dir   = rem >> 10;
    int b     = (rem >> 8) & 3;
    int tile  = rem & 255;
    int qset  = dir ^ 1;                   // dir0: queries=preds(set1), refs=gts
    int rset  = dir;

    size_t qoff = (size_t)(qset * BB + b) * NPTS + (size_t)tile * 32;
    size_t roff = (size_t)(rset * BB + b) * NPTS + (size_t)slice * RPS;
    int l31  = lane & 31;
    int half = lane >> 5;

    // A fragment: lanes 0-31 = query l31 (K slots 0-7); lanes 32-63 = zero.
    bf16x8 a = {0, 0, 0, 0, 0, 0, 0, 0};
    if (lane < 32) a = ((const bf16x8*)qpack)[qoff + l31];

    f32x16 zeroc;
    #pragma unroll
    for (int r = 0; r < 16; ++r) zeroc[r] = 0.0f;

    float macc[16];
    #pragma unroll
    for (int r = 0; r < 16; ++r) macc[r] = 3.0e38f;

    const bf16x8* rp = (const bf16x8*)refpack + roff;
    #pragma unroll 2
    for (int t = 0; t < RPS / 64; ++t) {   // 64 refs per iter
        bf16x8 b0 = rp[l31];
        bf16x8 b1 = rp[l31 + 32];
        rp += 64;
        f32x16 d0 = __builtin_amdgcn_mfma_f32_32x32x16_bf16(a, b0, zeroc, 0, 0, 0);
        f32x16 d1 = __builtin_amdgcn_mfma_f32_32x32x16_bf16(a, b1, zeroc, 0, 0, 0);
        #pragma unroll
        for (int r = 0; r < 16; ++r)
            macc[r] = fminf(fminf(d0[r], d1[r]), macc[r]);   // -> v_min3_f32
    }

    // Min across the 32 cols (lanes within each half), per row register.
    #pragma unroll
    for (int s = 1; s <= 16; s <<= 1) {
        #pragma unroll
        for (int r = 0; r < 16; ++r)
            macc[r] = fminf(macc[r], __shfl_xor(macc[r], s, 64));
    }

    // Lane r of each half writes row(r, half).
    float* mp = minpart + (size_t)slice * NQ_TOTAL
              + (size_t)(dir * BB + b) * NPTS + (size_t)tile * 32;
    #pragma unroll
    for (int r = 0; r < 16; ++r) {
        int row = (r & 3) + 8 * (r >> 2) + 4 * half;
        if (l31 == r) mp[row] = macc[r];
    }
}

// ---------------------------------------------------------------------------
// Kernel 3: merge slices, sqrt, block-reduce, atomicAdd into out[b].
// ---------------------------------------------------------------------------
__global__ __launch_bounds__(THREADS) void merge_kernel(
    const float* __restrict__ minpart, float* __restrict__ out) {
    int q = blockIdx.x * THREADS + threadIdx.x;    // 0 .. NQ_TOTAL-1
    float m = minpart[q];
    #pragma unroll
    for (int s = 1; s < SLICES; ++s)
        m = fminf(m, minpart[(size_t)s * NQ_TOTAL + q]);
    float d = sqrtf(fmaxf(m, 0.0f));
    int b = (q >> 13) & 3;                         // uniform within a block

    float sum = d;
    #pragma unroll
    for (int off = 32; off > 0; off >>= 1)
        sum += __shfl_down(sum, off, 64);

    __shared__ float wsum[THREADS / 64];
    int lane = threadIdx.x & 63;
    int wid  = threadIdx.x >> 6;
    if (lane == 0) wsum[wid] = sum;
    __syncthreads();
    if (threadIdx.x == 0)
        atomicAdd(out + b, wsum[0] + wsum[1] + wsum[2] + wsum[3]);
}

extern "C" void kernel_launch(void* const* d_in, const int* in_sizes, int n_in,
                              void* d_out, int out_size, void* d_ws, size_t ws_size,
                              hipStream_t stream) {
    const float* gts   = (const float*)d_in[0];
    const float* preds = (const float*)d_in[1];
    float* out = (float*)d_out;

    char* ws = (char*)d_ws;
    uint4* refpack = (uint4*)ws;                                   // 1 MiB
    uint4* qpack   = (uint4*)(ws + (size_t)NQ_TOTAL * 16);         // 1 MiB
    float* minpart = (float*)(ws + (size_t)NQ_TOTAL * 32);         // 512 KiB

    pack_kernel<<<NQ_TOTAL / THREADS, THREADS, 0, stream>>>(
        gts, preds, refpack, qpack, out);

    min_kernel<<<NBLK_MIN, THREADS, 0, stream>>>(refpack, qpack, minpart);

    merge_kernel<<<NQ_TOTAL / THREADS, THREADS, 0, stream>>>(minpart, out);
}